// Round 4
// baseline (296.988 us; speedup 1.0000x reference)
//
#include <hip/hip_runtime.h>

#define N_NODES 100000
#define D_IN 32
#define H 64
#define EPS 1e-5f
#define RSTR 32     // bucket row: 32 entry slots (128B)
#define CAP 32
#define OV_CAP 32768

typedef float floatx2 __attribute__((ext_vector_type(2)));

__device__ __forceinline__ unsigned short f2bf(float f) {
    union { float f; unsigned int u; } c; c.f = f;
    unsigned int b = c.u + 0x7FFFu + ((c.u >> 16) & 1u);   // RNE
    return (unsigned short)(b >> 16);
}
__device__ __forceinline__ float bf2f(unsigned short s) {
    union { unsigned int u; float f; } c; c.u = ((unsigned int)s) << 16;
    return c.f;
}

// ================= fused: scatter + MLP, Bresenham-interleaved roles =================
// R12 theory: both kernels are LATENCY-bound, not BW-bound (R11 disproved a
// write-BW limit: 1.57 TB/s mixed traffic in the same 105us; whole working
// set is L3-resident so TCC WRITE_SIZE is L2->L3, not HBM). Occupancy was
// capped at 25% by __launch_bounds__(256,2) (measured 21-24% = cap binding,
// VALUBusy 13%, all pipes idle -> waves parked in vmcnt waits on random-line
// atomics/stores). VGPR=68 allows 7 waves/SIMD; raise cap to 6 blocks/CU
// (VGPR budget 85). Whole 1002-block grid becomes co-resident; scatter and
// MLP overlap fully. bkt store made PLAIN (was nontemporal): allow L2 line
// retention so the ~12.5 writes/row can merge — decomposable via WRITE_SIZE.
__global__ __launch_bounds__(256, 6) void fused_kernel(
    const float* __restrict__ x,
    const float* __restrict__ W1, const float* __restrict__ b1,
    const float* __restrict__ g1, const float* __restrict__ be1,
    const float* __restrict__ W2, const float* __restrict__ b2,
    const float* __restrict__ g2, const float* __restrict__ be2,
    unsigned short* __restrict__ hb, unsigned char* __restrict__ hb8,
    const int* __restrict__ ei, int* __restrict__ cnt, int* __restrict__ bkt,
    int* __restrict__ ovCnt, int2* __restrict__ ov,
    int E, int SB, int TOT)
{
    const int i = blockIdx.x;
    const int before = (int)((long long)i * SB / TOT);
    const int after  = (int)((long long)(i + 1) * SB / TOT);

    if (after > before) {
        // ---------------- scatter: 8 edges/thread ----------------
        int t = before * 256 + threadIdx.x;
        int e0 = t * 8;
        if (e0 >= E) return;

        int rows[8], cols[8], pos[8];
        if (e0 + 7 < E) {
            int4 r0 = *(const int4*)(ei + e0);
            int4 r1 = *(const int4*)(ei + e0 + 4);
            int4 c0 = *(const int4*)(ei + E + e0);
            int4 c1 = *(const int4*)(ei + E + e0 + 4);
            rows[0]=r0.x; rows[1]=r0.y; rows[2]=r0.z; rows[3]=r0.w;
            rows[4]=r1.x; rows[5]=r1.y; rows[6]=r1.z; rows[7]=r1.w;
            cols[0]=c0.x; cols[1]=c0.y; cols[2]=c0.z; cols[3]=c0.w;
            cols[4]=c1.x; cols[5]=c1.y; cols[6]=c1.z; cols[7]=c1.w;
        } else {
#pragma unroll
            for (int j = 0; j < 8; ++j) {
                int e = e0 + j;
                if (e < E) { rows[j] = ei[e]; cols[j] = ei[E + e]; }
                else rows[j] = -1;
            }
        }
#pragma unroll
        for (int j = 0; j < 8; ++j)
            if (rows[j] >= 0) pos[j] = atomicAdd(&cnt[rows[j]], 1);
#pragma unroll
        for (int j = 0; j < 8; ++j) {
            if (rows[j] < 0) continue;
            if (pos[j] < CAP) {
                bkt[rows[j] * RSTR + pos[j]] = cols[j];   // plain: let L2 merge
            } else {
                int s = atomicAdd(ovCnt, 1);
                if (s < OV_CAP) ov[s] = make_int2(rows[j], cols[j]);
            }
        }
        return;
    }

    // ---------------- MLP: thread-per-node ----------------
    int gid = (i - before) * 256 + threadIdx.x;
    int node = gid < N_NODES ? gid : N_NODES - 1;

    float xr[D_IN];
    {
        const float4* xp = (const float4*)(x + (long long)node * D_IN);
#pragma unroll
        for (int i2 = 0; i2 < D_IN / 4; ++i2) {
            float4 v = xp[i2];
            xr[4*i2+0] = v.x; xr[4*i2+1] = v.y; xr[4*i2+2] = v.z; xr[4*i2+3] = v.w;
        }
    }

    float h1[H];
#pragma unroll
    for (int jb = 0; jb < H / 4; ++jb) {
        float4 b = *(const float4*)(b1 + jb * 4);
        h1[4*jb+0] = b.x; h1[4*jb+1] = b.y; h1[4*jb+2] = b.z; h1[4*jb+3] = b.w;
    }
#pragma unroll
    for (int k = 0; k < D_IN; ++k) {
        float xk = xr[k];
#pragma unroll
        for (int jb = 0; jb < H / 4; ++jb) {
            float4 w = *(const float4*)(W1 + k * H + jb * 4);
            h1[4*jb+0] += xk * w.x; h1[4*jb+1] += xk * w.y;
            h1[4*jb+2] += xk * w.z; h1[4*jb+3] += xk * w.w;
        }
    }
    {
        float s0=0,s1=0,s2=0,s3=0, q0=0,q1=0,q2=0,q3=0;
#pragma unroll
        for (int j = 0; j < H; j += 4) {
            s0 += h1[j+0]; s1 += h1[j+1]; s2 += h1[j+2]; s3 += h1[j+3];
            q0 += h1[j+0]*h1[j+0]; q1 += h1[j+1]*h1[j+1];
            q2 += h1[j+2]*h1[j+2]; q3 += h1[j+3]*h1[j+3];
        }
        float mu  = (s0+s1+s2+s3) * (1.0f / H);
        float var = (q0+q1+q2+q3) * (1.0f / H) - mu * mu;
        float rs  = rsqrtf(var + EPS);
#pragma unroll
        for (int jb = 0; jb < H / 4; ++jb) {
            float4 g = *(const float4*)(g1 + jb * 4);
            float4 be = *(const float4*)(be1 + jb * 4);
            h1[4*jb+0] = fmaxf((h1[4*jb+0]-mu)*rs*g.x + be.x, 0.0f);
            h1[4*jb+1] = fmaxf((h1[4*jb+1]-mu)*rs*g.y + be.y, 0.0f);
            h1[4*jb+2] = fmaxf((h1[4*jb+2]-mu)*rs*g.z + be.z, 0.0f);
            h1[4*jb+3] = fmaxf((h1[4*jb+3]-mu)*rs*g.w + be.w, 0.0f);
        }
    }

    float h2[H];
#pragma unroll
    for (int jb = 0; jb < H / 4; ++jb) {
        float4 b = *(const float4*)(b2 + jb * 4);
        h2[4*jb+0] = b.x; h2[4*jb+1] = b.y; h2[4*jb+2] = b.z; h2[4*jb+3] = b.w;
    }
#pragma unroll
    for (int k = 0; k < H; ++k) {
        float hk = h1[k];
#pragma unroll
        for (int jb = 0; jb < H / 4; ++jb) {
            float4 w = *(const float4*)(W2 + k * H + jb * 4);
            h2[4*jb+0] += hk * w.x; h2[4*jb+1] += hk * w.y;
            h2[4*jb+2] += hk * w.z; h2[4*jb+3] += hk * w.w;
        }
    }
    {
        float s0=0,s1=0,s2=0,s3=0, q0=0,q1=0,q2=0,q3=0;
#pragma unroll
        for (int j = 0; j < H; j += 4) {
            s0 += h2[j+0]; s1 += h2[j+1]; s2 += h2[j+2]; s3 += h2[j+3];
            q0 += h2[j+0]*h2[j+0]; q1 += h2[j+1]*h2[j+1];
            q2 += h2[j+2]*h2[j+2]; q3 += h2[j+3]*h2[j+3];
        }
        float mu  = (s0+s1+s2+s3) * (1.0f / H);
        float var = (q0+q1+q2+q3) * (1.0f / H) - mu * mu;
        float rs  = rsqrtf(var + EPS);

        unsigned short* hp = hb + (long long)node * H;
        unsigned int w8[H / 4];
#pragma unroll
        for (int jb = 0; jb < H / 4; ++jb) {
            float4 g = *(const float4*)(g2 + jb * 4);
            float4 be = *(const float4*)(be2 + jb * 4);
            float4 v;
            v.x = fmaxf((h2[4*jb+0]-mu)*rs*g.x + be.x, 0.0f);
            v.y = fmaxf((h2[4*jb+1]-mu)*rs*g.y + be.y, 0.0f);
            v.z = fmaxf((h2[4*jb+2]-mu)*rs*g.z + be.z, 0.0f);
            v.w = fmaxf((h2[4*jb+3]-mu)*rs*g.w + be.w, 0.0f);
            ushort4 u;
            u.x = f2bf(v.x); u.y = f2bf(v.y); u.z = f2bf(v.z); u.w = f2bf(v.w);
            *(ushort4*)(hp + 4*jb) = u;
            int lo = __builtin_amdgcn_cvt_pk_fp8_f32(v.x, v.y, 0, false);
            w8[jb] = (unsigned int)__builtin_amdgcn_cvt_pk_fp8_f32(v.z, v.w, lo, true);
        }
        unsigned int* hp8 = (unsigned int*)(hb8 + (long long)node * H);
#pragma unroll
        for (int q = 0; q < H / 16; ++q)
            *(uint4*)(hp8 + q * 4) = make_uint4(w8[4*q+0], w8[4*q+1], w8[4*q+2], w8[4*q+3]);
    }
}

// ================= pull aggregation: fp8 gathers (64B rows) =================
// Same occupancy lever: (256,2)->(256,6). Gather path is latency-bound
// (random 64B lines); 3x waves = 3x outstanding gathers.
__global__ __launch_bounds__(256, 6) void aggr_kernel(
    const int* __restrict__ cnt, const int* __restrict__ bkt,
    const unsigned short* __restrict__ hb, const unsigned char* __restrict__ hb8,
    float* __restrict__ out,
    const int* __restrict__ ovCnt, const int2* __restrict__ ov)
{
    const int t    = threadIdx.x & 63;
    const int sub  = t >> 4;                       // node-within-wave
    const int c    = t & 15;                       // channel quad
    const int wave = blockIdx.x * 4 + (threadIdx.x >> 6);
    const int node = wave * 4 + sub;               // grid exact: 6250*16 = 100000

    int m = cnt[node];
    if (m > CAP) m = CAP;
    const int base = node * RSTR;
    const unsigned int* h8 = (const unsigned int*)hb8;  // row stride 16 uints

    float a0 = 0.f, a1 = 0.f, a2 = 0.f, a3 = 0.f;
#pragma unroll
    for (int j0 = 0; j0 < CAP; j0 += 16) {
        int cc[16];
#pragma unroll
        for (int i = 0; i < 16; ++i)               // broadcast loads (16 lanes/addr)
            cc[i] = bkt[base + j0 + i];
        unsigned int vv[16];
#pragma unroll
        for (int i = 0; i < 16; ++i)               // independent 4B gathers (64B/row)
            if (j0 + i < m) vv[i] = h8[(cc[i] << 4) + c];
#pragma unroll
        for (int i = 0; i < 16; ++i) {
            if (j0 + i < m) {
                floatx2 p0 = __builtin_amdgcn_cvt_pk_f32_fp8(vv[i], false);
                floatx2 p1 = __builtin_amdgcn_cvt_pk_f32_fp8(vv[i], true);
                a0 += p0.x; a1 += p0.y; a2 += p1.x; a3 += p1.y;
            }
        }
    }

    // self term (bf16 precision, sequential access)
    {
        uint2 sv = *(const uint2*)(hb + ((long long)node << 6) + (c << 2));
        a0 += bf2f((unsigned short)(sv.x & 0xFFFFu));
        a1 += bf2f((unsigned short)(sv.x >> 16));
        a2 += bf2f((unsigned short)(sv.y & 0xFFFFu));
        a3 += bf2f((unsigned short)(sv.y >> 16));
    }

    // exact overflow drain (normally 0 entries)
    int nov = *ovCnt; if (nov > OV_CAP) nov = OV_CAP;
    for (int i = 0; i < nov; ++i) {
        int2 rc = ov[i];
        if (rc.x == node) {
            uint2 vv = *(const uint2*)(hb + ((long long)rc.y << 6) + (c << 2));
            a0 += bf2f((unsigned short)(vv.x & 0xFFFFu));
            a1 += bf2f((unsigned short)(vv.x >> 16));
            a2 += bf2f((unsigned short)(vv.y & 0xFFFFu));
            a3 += bf2f((unsigned short)(vv.y >> 16));
        }
    }

    *(float4*)(out + ((long long)node << 6) + (c << 2)) = make_float4(a0, a1, a2, a3);
}

extern "C" void kernel_launch(void* const* d_in, const int* in_sizes, int n_in,
                              void* d_out, int out_size, void* d_ws, size_t ws_size,
                              hipStream_t stream)
{
    const float* x   = (const float*)d_in[0];
    const int*   ei  = (const int*)d_in[1];
    const float* W1  = (const float*)d_in[2];
    const float* b1  = (const float*)d_in[3];
    const float* g1  = (const float*)d_in[4];
    const float* be1 = (const float*)d_in[5];
    const float* W2  = (const float*)d_in[6];
    const float* b2  = (const float*)d_in[7];
    const float* g2  = (const float*)d_in[8];
    const float* be2 = (const float*)d_in[9];

    float* out = (float*)d_out;

    // workspace layout (~32.7 MB)
    char* ws = (char*)d_ws;
    unsigned short* hb    = (unsigned short*)ws;        // 12,800,000 B
    unsigned char*  hb8   = (unsigned char*)(ws + 12800000); // 6,400,000 B
    int*            cnt   = (int*)(ws + 19200000);      //    400,000 B
    int*            ovCnt = (int*)(ws + 19600000);      //         64 B
    int2*           ov    = (int2*)(ws + 19600064);     //    262,144 B
    int*            bkt   = (int*)(ws + 19862208);      // 12,800,000 B (never zeroed)

    const int E = in_sizes[1] / 2;

    (void)hipMemsetAsync(cnt, 0, 400064, stream);       // cnt + ovCnt

    const int SB = ((E + 7) / 8 + 255) / 256;           // 611 scatter blocks
    const int MB = (N_NODES + 255) / 256;               // 391 mlp blocks
    fused_kernel<<<SB + MB, 256, 0, stream>>>(
        x, W1, b1, g1, be1, W2, b2, g2, be2, hb, hb8,
        ei, cnt, bkt, ovCnt, ov, E, SB, SB + MB);

    aggr_kernel<<<N_NODES / 16, 256, 0, stream>>>(cnt, bkt, hb, hb8, out, ovCnt, ov);
}

// Round 5
// 242.734 us; speedup vs baseline: 1.2235x; 1.2235x over previous
//
#include <hip/hip_runtime.h>

#define N_NODES 100000
#define D_IN 32
#define H 64
#define EPS 1e-5f
#define RSTR 32     // bucket row: 32 entry slots (128B)
#define CAP 32
#define OV_CAP 32768

typedef float floatx2 __attribute__((ext_vector_type(2)));

__device__ __forceinline__ unsigned short f2bf(float f) {
    union { float f; unsigned int u; } c; c.f = f;
    unsigned int b = c.u + 0x7FFFu + ((c.u >> 16) & 1u);   // RNE
    return (unsigned short)(b >> 16);
}
__device__ __forceinline__ float bf2f(unsigned short s) {
    union { unsigned int u; float f; } c; c.u = ((unsigned int)s) << 16;
    return c.f;
}

// ================= fused: scatter + MLP, Bresenham-interleaved roles =================
// R13: occupancy lever, un-confounded. R12's (256,6) forced VGPR 68->40 ->
// massive scratch spill (WRITE 243 MB, dur 192us) — the latency theory was
// never tested. (256,4) keeps the VGPR budget at 128/wave (>=68, no spill)
// and raises the occupancy cap 25%->50%; grid is 1002 blocks ~= 3.9/CU so
// cap 4 already gives full residency. Single delta vs the 206us baseline.
// GUARD: VGPR_Count must stay 68 in the profile, else this round is invalid.
__global__ __launch_bounds__(256, 4) void fused_kernel(
    const float* __restrict__ x,
    const float* __restrict__ W1, const float* __restrict__ b1,
    const float* __restrict__ g1, const float* __restrict__ be1,
    const float* __restrict__ W2, const float* __restrict__ b2,
    const float* __restrict__ g2, const float* __restrict__ be2,
    unsigned short* __restrict__ hb, unsigned char* __restrict__ hb8,
    const int* __restrict__ ei, int* __restrict__ cnt, int* __restrict__ bkt,
    int* __restrict__ ovCnt, int2* __restrict__ ov,
    int E, int SB, int TOT)
{
    const int i = blockIdx.x;
    const int before = (int)((long long)i * SB / TOT);
    const int after  = (int)((long long)(i + 1) * SB / TOT);

    if (after > before) {
        // ---------------- scatter: 8 edges/thread ----------------
        int t = before * 256 + threadIdx.x;
        int e0 = t * 8;
        if (e0 >= E) return;

        int rows[8], cols[8], pos[8];
        if (e0 + 7 < E) {
            int4 r0 = *(const int4*)(ei + e0);
            int4 r1 = *(const int4*)(ei + e0 + 4);
            int4 c0 = *(const int4*)(ei + E + e0);
            int4 c1 = *(const int4*)(ei + E + e0 + 4);
            rows[0]=r0.x; rows[1]=r0.y; rows[2]=r0.z; rows[3]=r0.w;
            rows[4]=r1.x; rows[5]=r1.y; rows[6]=r1.z; rows[7]=r1.w;
            cols[0]=c0.x; cols[1]=c0.y; cols[2]=c0.z; cols[3]=c0.w;
            cols[4]=c1.x; cols[5]=c1.y; cols[6]=c1.z; cols[7]=c1.w;
        } else {
#pragma unroll
            for (int j = 0; j < 8; ++j) {
                int e = e0 + j;
                if (e < E) { rows[j] = ei[e]; cols[j] = ei[E + e]; }
                else rows[j] = -1;
            }
        }
#pragma unroll
        for (int j = 0; j < 8; ++j)
            if (rows[j] >= 0) pos[j] = atomicAdd(&cnt[rows[j]], 1);
#pragma unroll
        for (int j = 0; j < 8; ++j) {
            if (rows[j] < 0) continue;
            if (pos[j] < CAP) {
                __builtin_nontemporal_store(cols[j], &bkt[rows[j] * RSTR + pos[j]]);
            } else {
                int s = atomicAdd(ovCnt, 1);
                if (s < OV_CAP) ov[s] = make_int2(rows[j], cols[j]);
            }
        }
        return;
    }

    // ---------------- MLP: thread-per-node ----------------
    int gid = (i - before) * 256 + threadIdx.x;
    int node = gid < N_NODES ? gid : N_NODES - 1;

    float xr[D_IN];
    {
        const float4* xp = (const float4*)(x + (long long)node * D_IN);
#pragma unroll
        for (int i2 = 0; i2 < D_IN / 4; ++i2) {
            float4 v = xp[i2];
            xr[4*i2+0] = v.x; xr[4*i2+1] = v.y; xr[4*i2+2] = v.z; xr[4*i2+3] = v.w;
        }
    }

    float h1[H];
#pragma unroll
    for (int jb = 0; jb < H / 4; ++jb) {
        float4 b = *(const float4*)(b1 + jb * 4);
        h1[4*jb+0] = b.x; h1[4*jb+1] = b.y; h1[4*jb+2] = b.z; h1[4*jb+3] = b.w;
    }
#pragma unroll
    for (int k = 0; k < D_IN; ++k) {
        float xk = xr[k];
#pragma unroll
        for (int jb = 0; jb < H / 4; ++jb) {
            float4 w = *(const float4*)(W1 + k * H + jb * 4);
            h1[4*jb+0] += xk * w.x; h1[4*jb+1] += xk * w.y;
            h1[4*jb+2] += xk * w.z; h1[4*jb+3] += xk * w.w;
        }
    }
    {
        float s0=0,s1=0,s2=0,s3=0, q0=0,q1=0,q2=0,q3=0;
#pragma unroll
        for (int j = 0; j < H; j += 4) {
            s0 += h1[j+0]; s1 += h1[j+1]; s2 += h1[j+2]; s3 += h1[j+3];
            q0 += h1[j+0]*h1[j+0]; q1 += h1[j+1]*h1[j+1];
            q2 += h1[j+2]*h1[j+2]; q3 += h1[j+3]*h1[j+3];
        }
        float mu  = (s0+s1+s2+s3) * (1.0f / H);
        float var = (q0+q1+q2+q3) * (1.0f / H) - mu * mu;
        float rs  = rsqrtf(var + EPS);
#pragma unroll
        for (int jb = 0; jb < H / 4; ++jb) {
            float4 g = *(const float4*)(g1 + jb * 4);
            float4 be = *(const float4*)(be1 + jb * 4);
            h1[4*jb+0] = fmaxf((h1[4*jb+0]-mu)*rs*g.x + be.x, 0.0f);
            h1[4*jb+1] = fmaxf((h1[4*jb+1]-mu)*rs*g.y + be.y, 0.0f);
            h1[4*jb+2] = fmaxf((h1[4*jb+2]-mu)*rs*g.z + be.z, 0.0f);
            h1[4*jb+3] = fmaxf((h1[4*jb+3]-mu)*rs*g.w + be.w, 0.0f);
        }
    }

    float h2[H];
#pragma unroll
    for (int jb = 0; jb < H / 4; ++jb) {
        float4 b = *(const float4*)(b2 + jb * 4);
        h2[4*jb+0] = b.x; h2[4*jb+1] = b.y; h2[4*jb+2] = b.z; h2[4*jb+3] = b.w;
    }
#pragma unroll
    for (int k = 0; k < H; ++k) {
        float hk = h1[k];
#pragma unroll
        for (int jb = 0; jb < H / 4; ++jb) {
            float4 w = *(const float4*)(W2 + k * H + jb * 4);
            h2[4*jb+0] += hk * w.x; h2[4*jb+1] += hk * w.y;
            h2[4*jb+2] += hk * w.z; h2[4*jb+3] += hk * w.w;
        }
    }
    {
        float s0=0,s1=0,s2=0,s3=0, q0=0,q1=0,q2=0,q3=0;
#pragma unroll
        for (int j = 0; j < H; j += 4) {
            s0 += h2[j+0]; s1 += h2[j+1]; s2 += h2[j+2]; s3 += h2[j+3];
            q0 += h2[j+0]*h2[j+0]; q1 += h2[j+1]*h2[j+1];
            q2 += h2[j+2]*h2[j+2]; q3 += h2[j+3]*h2[j+3];
        }
        float mu  = (s0+s1+s2+s3) * (1.0f / H);
        float var = (q0+q1+q2+q3) * (1.0f / H) - mu * mu;
        float rs  = rsqrtf(var + EPS);

        unsigned short* hp = hb + (long long)node * H;
        unsigned int w8[H / 4];
#pragma unroll
        for (int jb = 0; jb < H / 4; ++jb) {
            float4 g = *(const float4*)(g2 + jb * 4);
            float4 be = *(const float4*)(be2 + jb * 4);
            float4 v;
            v.x = fmaxf((h2[4*jb+0]-mu)*rs*g.x + be.x, 0.0f);
            v.y = fmaxf((h2[4*jb+1]-mu)*rs*g.y + be.y, 0.0f);
            v.z = fmaxf((h2[4*jb+2]-mu)*rs*g.z + be.z, 0.0f);
            v.w = fmaxf((h2[4*jb+3]-mu)*rs*g.w + be.w, 0.0f);
            ushort4 u;
            u.x = f2bf(v.x); u.y = f2bf(v.y); u.z = f2bf(v.z); u.w = f2bf(v.w);
            *(ushort4*)(hp + 4*jb) = u;
            int lo = __builtin_amdgcn_cvt_pk_fp8_f32(v.x, v.y, 0, false);
            w8[jb] = (unsigned int)__builtin_amdgcn_cvt_pk_fp8_f32(v.z, v.w, lo, true);
        }
        unsigned int* hp8 = (unsigned int*)(hb8 + (long long)node * H);
#pragma unroll
        for (int q = 0; q < H / 16; ++q)
            *(uint4*)(hp8 + q * 4) = make_uint4(w8[4*q+0], w8[4*q+1], w8[4*q+2], w8[4*q+3]);
    }
}

// ================= pull aggregation: fp8 gathers (64B rows) =================
// Same un-confounded occupancy lever: (256,2)->(256,4). Gather path is
// latency-bound (random 64B lines); 2x waves = 2x outstanding gathers.
__global__ __launch_bounds__(256, 4) void aggr_kernel(
    const int* __restrict__ cnt, const int* __restrict__ bkt,
    const unsigned short* __restrict__ hb, const unsigned char* __restrict__ hb8,
    float* __restrict__ out,
    const int* __restrict__ ovCnt, const int2* __restrict__ ov)
{
    const int t    = threadIdx.x & 63;
    const int sub  = t >> 4;                       // node-within-wave
    const int c    = t & 15;                       // channel quad
    const int wave = blockIdx.x * 4 + (threadIdx.x >> 6);
    const int node = wave * 4 + sub;               // grid exact: 6250*16 = 100000

    int m = cnt[node];
    if (m > CAP) m = CAP;
    const int base = node * RSTR;
    const unsigned int* h8 = (const unsigned int*)hb8;  // row stride 16 uints

    float a0 = 0.f, a1 = 0.f, a2 = 0.f, a3 = 0.f;
#pragma unroll
    for (int j0 = 0; j0 < CAP; j0 += 16) {
        int cc[16];
#pragma unroll
        for (int i = 0; i < 16; ++i)               // broadcast loads (16 lanes/addr)
            cc[i] = bkt[base + j0 + i];
        unsigned int vv[16];
#pragma unroll
        for (int i = 0; i < 16; ++i)               // independent 4B gathers (64B/row)
            if (j0 + i < m) vv[i] = h8[(cc[i] << 4) + c];
#pragma unroll
        for (int i = 0; i < 16; ++i) {
            if (j0 + i < m) {
                floatx2 p0 = __builtin_amdgcn_cvt_pk_f32_fp8(vv[i], false);
                floatx2 p1 = __builtin_amdgcn_cvt_pk_f32_fp8(vv[i], true);
                a0 += p0.x; a1 += p0.y; a2 += p1.x; a3 += p1.y;
            }
        }
    }

    // self term (bf16 precision, sequential access)
    {
        uint2 sv = *(const uint2*)(hb + ((long long)node << 6) + (c << 2));
        a0 += bf2f((unsigned short)(sv.x & 0xFFFFu));
        a1 += bf2f((unsigned short)(sv.x >> 16));
        a2 += bf2f((unsigned short)(sv.y & 0xFFFFu));
        a3 += bf2f((unsigned short)(sv.y >> 16));
    }

    // exact overflow drain (normally 0 entries)
    int nov = *ovCnt; if (nov > OV_CAP) nov = OV_CAP;
    for (int i = 0; i < nov; ++i) {
        int2 rc = ov[i];
        if (rc.x == node) {
            uint2 vv = *(const uint2*)(hb + ((long long)rc.y << 6) + (c << 2));
            a0 += bf2f((unsigned short)(vv.x & 0xFFFFu));
            a1 += bf2f((unsigned short)(vv.x >> 16));
            a2 += bf2f((unsigned short)(vv.y & 0xFFFFu));
            a3 += bf2f((unsigned short)(vv.y >> 16));
        }
    }

    *(float4*)(out + ((long long)node << 6) + (c << 2)) = make_float4(a0, a1, a2, a3);
}

extern "C" void kernel_launch(void* const* d_in, const int* in_sizes, int n_in,
                              void* d_out, int out_size, void* d_ws, size_t ws_size,
                              hipStream_t stream)
{
    const float* x   = (const float*)d_in[0];
    const int*   ei  = (const int*)d_in[1];
    const float* W1  = (const float*)d_in[2];
    const float* b1  = (const float*)d_in[3];
    const float* g1  = (const float*)d_in[4];
    const float* be1 = (const float*)d_in[5];
    const float* W2  = (const float*)d_in[6];
    const float* b2  = (const float*)d_in[7];
    const float* g2  = (const float*)d_in[8];
    const float* be2 = (const float*)d_in[9];

    float* out = (float*)d_out;

    // workspace layout (~32.7 MB)
    char* ws = (char*)d_ws;
    unsigned short* hb    = (unsigned short*)ws;        // 12,800,000 B
    unsigned char*  hb8   = (unsigned char*)(ws + 12800000); // 6,400,000 B
    int*            cnt   = (int*)(ws + 19200000);      //    400,000 B
    int*            ovCnt = (int*)(ws + 19600000);      //         64 B
    int2*           ov    = (int2*)(ws + 19600064);     //    262,144 B
    int*            bkt   = (int*)(ws + 19862208);      // 12,800,000 B (nt-written, never zeroed)

    const int E = in_sizes[1] / 2;

    (void)hipMemsetAsync(cnt, 0, 400064, stream);       // cnt + ovCnt

    const int SB = ((E + 7) / 8 + 255) / 256;           // 611 scatter blocks
    const int MB = (N_NODES + 255) / 256;               // 391 mlp blocks
    fused_kernel<<<SB + MB, 256, 0, stream>>>(
        x, W1, b1, g1, be1, W2, b2, g2, be2, hb, hb8,
        ei, cnt, bkt, ovCnt, ov, E, SB, SB + MB);

    aggr_kernel<<<N_NODES / 16, 256, 0, stream>>>(cnt, bkt, hb, hb8, out, ovCnt, ov);
}

// Round 6
// 208.936 us; speedup vs baseline: 1.4214x; 1.1618x over previous
//
#include <hip/hip_runtime.h>

#define N_NODES 100000
#define D_IN 32
#define H 64
#define EPS 1e-5f
#define RSTR 32     // bucket row: 32 entry slots (128B)
#define CAP 32
#define OV_CAP 32768
#define CSTR 16     // cnt stride: 1 counter per 64B line (atomic same-line contention 200 -> 12.5)

typedef float floatx2 __attribute__((ext_vector_type(2)));

__device__ __forceinline__ unsigned short f2bf(float f) {
    union { float f; unsigned int u; } c; c.f = f;
    unsigned int b = c.u + 0x7FFFu + ((c.u >> 16) & 1u);   // RNE
    return (unsigned short)(b >> 16);
}
__device__ __forceinline__ float bf2f(unsigned short s) {
    union { unsigned int u; float f; } c; c.u = ((unsigned int)s) << 16;
    return c.f;
}

// ================= fused: scatter + MLP, Bresenham-interleaved roles =================
// R14 theory: the 105us fused floor is the device-scope atomic stream.
// Evidence: R0 vs R3 moved 1.0 vs 1.57 TB/s in the SAME 105us (not BW);
// occupancy 21-28% across rounds with no dur effect (not concurrency in that
// range); VALU work ~10us (not compute). Constant across all: 1.25M
// atomicAdds to cnt. gfx950 L2s aren't cross-XCD coherent -> device atomics
// execute at the L3/fabric RMW point; cnt packs 16 counters/64B line -> 200
// same-line RMWs serialized per line ~= the observed 105us. Fix under test:
// stride cnt to 1 counter/line (CSTR=16) -> 12.5 atomics/line, same count.
// Everything else reverted to the 206us R0 baseline ((256,2), nt bkt store).
// GUARD: VGPR must be 68 again, else codegen drifted and round is invalid.
__global__ __launch_bounds__(256, 2) void fused_kernel(
    const float* __restrict__ x,
    const float* __restrict__ W1, const float* __restrict__ b1,
    const float* __restrict__ g1, const float* __restrict__ be1,
    const float* __restrict__ W2, const float* __restrict__ b2,
    const float* __restrict__ g2, const float* __restrict__ be2,
    unsigned short* __restrict__ hb, unsigned char* __restrict__ hb8,
    const int* __restrict__ ei, int* __restrict__ cnt, int* __restrict__ bkt,
    int* __restrict__ ovCnt, int2* __restrict__ ov,
    int E, int SB, int TOT)
{
    const int i = blockIdx.x;
    const int before = (int)((long long)i * SB / TOT);
    const int after  = (int)((long long)(i + 1) * SB / TOT);

    if (after > before) {
        // ---------------- scatter: 8 edges/thread ----------------
        int t = before * 256 + threadIdx.x;
        int e0 = t * 8;
        if (e0 >= E) return;

        int rows[8], cols[8], pos[8];
        if (e0 + 7 < E) {
            int4 r0 = *(const int4*)(ei + e0);
            int4 r1 = *(const int4*)(ei + e0 + 4);
            int4 c0 = *(const int4*)(ei + E + e0);
            int4 c1 = *(const int4*)(ei + E + e0 + 4);
            rows[0]=r0.x; rows[1]=r0.y; rows[2]=r0.z; rows[3]=r0.w;
            rows[4]=r1.x; rows[5]=r1.y; rows[6]=r1.z; rows[7]=r1.w;
            cols[0]=c0.x; cols[1]=c0.y; cols[2]=c0.z; cols[3]=c0.w;
            cols[4]=c1.x; cols[5]=c1.y; cols[6]=c1.z; cols[7]=c1.w;
        } else {
#pragma unroll
            for (int j = 0; j < 8; ++j) {
                int e = e0 + j;
                if (e < E) { rows[j] = ei[e]; cols[j] = ei[E + e]; }
                else rows[j] = -1;
            }
        }
#pragma unroll
        for (int j = 0; j < 8; ++j)
            if (rows[j] >= 0) pos[j] = atomicAdd(&cnt[rows[j] * CSTR], 1);
#pragma unroll
        for (int j = 0; j < 8; ++j) {
            if (rows[j] < 0) continue;
            if (pos[j] < CAP) {
                __builtin_nontemporal_store(cols[j], &bkt[rows[j] * RSTR + pos[j]]);
            } else {
                int s = atomicAdd(ovCnt, 1);
                if (s < OV_CAP) ov[s] = make_int2(rows[j], cols[j]);
            }
        }
        return;
    }

    // ---------------- MLP: thread-per-node ----------------
    int gid = (i - before) * 256 + threadIdx.x;
    int node = gid < N_NODES ? gid : N_NODES - 1;

    float xr[D_IN];
    {
        const float4* xp = (const float4*)(x + (long long)node * D_IN);
#pragma unroll
        for (int i2 = 0; i2 < D_IN / 4; ++i2) {
            float4 v = xp[i2];
            xr[4*i2+0] = v.x; xr[4*i2+1] = v.y; xr[4*i2+2] = v.z; xr[4*i2+3] = v.w;
        }
    }

    float h1[H];
#pragma unroll
    for (int jb = 0; jb < H / 4; ++jb) {
        float4 b = *(const float4*)(b1 + jb * 4);
        h1[4*jb+0] = b.x; h1[4*jb+1] = b.y; h1[4*jb+2] = b.z; h1[4*jb+3] = b.w;
    }
#pragma unroll
    for (int k = 0; k < D_IN; ++k) {
        float xk = xr[k];
#pragma unroll
        for (int jb = 0; jb < H / 4; ++jb) {
            float4 w = *(const float4*)(W1 + k * H + jb * 4);
            h1[4*jb+0] += xk * w.x; h1[4*jb+1] += xk * w.y;
            h1[4*jb+2] += xk * w.z; h1[4*jb+3] += xk * w.w;
        }
    }
    {
        float s0=0,s1=0,s2=0,s3=0, q0=0,q1=0,q2=0,q3=0;
#pragma unroll
        for (int j = 0; j < H; j += 4) {
            s0 += h1[j+0]; s1 += h1[j+1]; s2 += h1[j+2]; s3 += h1[j+3];
            q0 += h1[j+0]*h1[j+0]; q1 += h1[j+1]*h1[j+1];
            q2 += h1[j+2]*h1[j+2]; q3 += h1[j+3]*h1[j+3];
        }
        float mu  = (s0+s1+s2+s3) * (1.0f / H);
        float var = (q0+q1+q2+q3) * (1.0f / H) - mu * mu;
        float rs  = rsqrtf(var + EPS);
#pragma unroll
        for (int jb = 0; jb < H / 4; ++jb) {
            float4 g = *(const float4*)(g1 + jb * 4);
            float4 be = *(const float4*)(be1 + jb * 4);
            h1[4*jb+0] = fmaxf((h1[4*jb+0]-mu)*rs*g.x + be.x, 0.0f);
            h1[4*jb+1] = fmaxf((h1[4*jb+1]-mu)*rs*g.y + be.y, 0.0f);
            h1[4*jb+2] = fmaxf((h1[4*jb+2]-mu)*rs*g.z + be.z, 0.0f);
            h1[4*jb+3] = fmaxf((h1[4*jb+3]-mu)*rs*g.w + be.w, 0.0f);
        }
    }

    float h2[H];
#pragma unroll
    for (int jb = 0; jb < H / 4; ++jb) {
        float4 b = *(const float4*)(b2 + jb * 4);
        h2[4*jb+0] = b.x; h2[4*jb+1] = b.y; h2[4*jb+2] = b.z; h2[4*jb+3] = b.w;
    }
#pragma unroll
    for (int k = 0; k < H; ++k) {
        float hk = h1[k];
#pragma unroll
        for (int jb = 0; jb < H / 4; ++jb) {
            float4 w = *(const float4*)(W2 + k * H + jb * 4);
            h2[4*jb+0] += hk * w.x; h2[4*jb+1] += hk * w.y;
            h2[4*jb+2] += hk * w.z; h2[4*jb+3] += hk * w.w;
        }
    }
    {
        float s0=0,s1=0,s2=0,s3=0, q0=0,q1=0,q2=0,q3=0;
#pragma unroll
        for (int j = 0; j < H; j += 4) {
            s0 += h2[j+0]; s1 += h2[j+1]; s2 += h2[j+2]; s3 += h2[j+3];
            q0 += h2[j+0]*h2[j+0]; q1 += h2[j+1]*h2[j+1];
            q2 += h2[j+2]*h2[j+2]; q3 += h2[j+3]*h2[j+3];
        }
        float mu  = (s0+s1+s2+s3) * (1.0f / H);
        float var = (q0+q1+q2+q3) * (1.0f / H) - mu * mu;
        float rs  = rsqrtf(var + EPS);

        unsigned short* hp = hb + (long long)node * H;
        unsigned int w8[H / 4];
#pragma unroll
        for (int jb = 0; jb < H / 4; ++jb) {
            float4 g = *(const float4*)(g2 + jb * 4);
            float4 be = *(const float4*)(be2 + jb * 4);
            float4 v;
            v.x = fmaxf((h2[4*jb+0]-mu)*rs*g.x + be.x, 0.0f);
            v.y = fmaxf((h2[4*jb+1]-mu)*rs*g.y + be.y, 0.0f);
            v.z = fmaxf((h2[4*jb+2]-mu)*rs*g.z + be.z, 0.0f);
            v.w = fmaxf((h2[4*jb+3]-mu)*rs*g.w + be.w, 0.0f);
            ushort4 u;
            u.x = f2bf(v.x); u.y = f2bf(v.y); u.z = f2bf(v.z); u.w = f2bf(v.w);
            *(ushort4*)(hp + 4*jb) = u;
            int lo = __builtin_amdgcn_cvt_pk_fp8_f32(v.x, v.y, 0, false);
            w8[jb] = (unsigned int)__builtin_amdgcn_cvt_pk_fp8_f32(v.z, v.w, lo, true);
        }
        unsigned int* hp8 = (unsigned int*)(hb8 + (long long)node * H);
#pragma unroll
        for (int q = 0; q < H / 16; ++q)
            *(uint4*)(hp8 + q * 4) = make_uint4(w8[4*q+0], w8[4*q+1], w8[4*q+2], w8[4*q+3]);
    }
}

// ================= pull aggregation: fp8 gathers (64B rows) =================
// unchanged vs R0 except strided cnt read (isolate the atomic-stride change)
__global__ __launch_bounds__(256, 2) void aggr_kernel(
    const int* __restrict__ cnt, const int* __restrict__ bkt,
    const unsigned short* __restrict__ hb, const unsigned char* __restrict__ hb8,
    float* __restrict__ out,
    const int* __restrict__ ovCnt, const int2* __restrict__ ov)
{
    const int t    = threadIdx.x & 63;
    const int sub  = t >> 4;                       // node-within-wave
    const int c    = t & 15;                       // channel quad
    const int wave = blockIdx.x * 4 + (threadIdx.x >> 6);
    const int node = wave * 4 + sub;               // grid exact: 6250*16 = 100000

    int m = cnt[node * CSTR];
    if (m > CAP) m = CAP;
    const int base = node * RSTR;
    const unsigned int* h8 = (const unsigned int*)hb8;  // row stride 16 uints

    float a0 = 0.f, a1 = 0.f, a2 = 0.f, a3 = 0.f;
#pragma unroll
    for (int j0 = 0; j0 < CAP; j0 += 16) {
        int cc[16];
#pragma unroll
        for (int i = 0; i < 16; ++i)               // broadcast loads (16 lanes/addr)
            cc[i] = bkt[base + j0 + i];
        unsigned int vv[16];
#pragma unroll
        for (int i = 0; i < 16; ++i)               // independent 4B gathers (64B/row)
            if (j0 + i < m) vv[i] = h8[(cc[i] << 4) + c];
#pragma unroll
        for (int i = 0; i < 16; ++i) {
            if (j0 + i < m) {
                floatx2 p0 = __builtin_amdgcn_cvt_pk_f32_fp8(vv[i], false);
                floatx2 p1 = __builtin_amdgcn_cvt_pk_f32_fp8(vv[i], true);
                a0 += p0.x; a1 += p0.y; a2 += p1.x; a3 += p1.y;
            }
        }
    }

    // self term (bf16 precision, sequential access)
    {
        uint2 sv = *(const uint2*)(hb + ((long long)node << 6) + (c << 2));
        a0 += bf2f((unsigned short)(sv.x & 0xFFFFu));
        a1 += bf2f((unsigned short)(sv.x >> 16));
        a2 += bf2f((unsigned short)(sv.y & 0xFFFFu));
        a3 += bf2f((unsigned short)(sv.y >> 16));
    }

    // exact overflow drain (normally 0 entries)
    int nov = *ovCnt; if (nov > OV_CAP) nov = OV_CAP;
    for (int i = 0; i < nov; ++i) {
        int2 rc = ov[i];
        if (rc.x == node) {
            uint2 vv = *(const uint2*)(hb + ((long long)rc.y << 6) + (c << 2));
            a0 += bf2f((unsigned short)(vv.x & 0xFFFFu));
            a1 += bf2f((unsigned short)(vv.x >> 16));
            a2 += bf2f((unsigned short)(vv.y & 0xFFFFu));
            a3 += bf2f((unsigned short)(vv.y >> 16));
        }
    }

    *(float4*)(out + ((long long)node << 6) + (c << 2)) = make_float4(a0, a1, a2, a3);
}

extern "C" void kernel_launch(void* const* d_in, const int* in_sizes, int n_in,
                              void* d_out, int out_size, void* d_ws, size_t ws_size,
                              hipStream_t stream)
{
    const float* x   = (const float*)d_in[0];
    const int*   ei  = (const int*)d_in[1];
    const float* W1  = (const float*)d_in[2];
    const float* b1  = (const float*)d_in[3];
    const float* g1  = (const float*)d_in[4];
    const float* be1 = (const float*)d_in[5];
    const float* W2  = (const float*)d_in[6];
    const float* b2  = (const float*)d_in[7];
    const float* g2  = (const float*)d_in[8];
    const float* be2 = (const float*)d_in[9];

    float* out = (float*)d_out;

    // workspace layout (~38.7 MB; cnt strided to 1 counter / 64B line)
    char* ws = (char*)d_ws;
    unsigned short* hb    = (unsigned short*)ws;             // 12,800,000 B
    unsigned char*  hb8   = (unsigned char*)(ws + 12800000); //  6,400,000 B
    int*            cnt   = (int*)(ws + 19200000);           //  6,400,000 B (strided)
    int*            ovCnt = (int*)(ws + 25600000);           //         64 B
    int2*           ov    = (int2*)(ws + 25600064);          //    262,144 B
    int*            bkt   = (int*)(ws + 25862208);           // 12,800,000 B (nt-written, never zeroed)

    const int E = in_sizes[1] / 2;

    (void)hipMemsetAsync(cnt, 0, 6400064, stream);           // cnt (strided) + ovCnt

    const int SB = ((E + 7) / 8 + 255) / 256;           // 611 scatter blocks
    const int MB = (N_NODES + 255) / 256;               // 391 mlp blocks
    fused_kernel<<<SB + MB, 256, 0, stream>>>(
        x, W1, b1, g1, be1, W2, b2, g2, be2, hb, hb8,
        ei, cnt, bkt, ovCnt, ov, E, SB, SB + MB);

    aggr_kernel<<<N_NODES / 16, 256, 0, stream>>>(cnt, bkt, hb, hb8, out, ovCnt, ov);
}